// Round 1
// baseline (3451.756 us; speedup 1.0000x reference)
//
#include <hip/hip_runtime.h>
#include <math.h>

// Problem constants (match reference)
#define B_   512
#define C_   3
#define T_   500
#define D_   40
#define CD_  120          // C*D
#define N_   256
#define OUT_ 12
#define G_   2            // batch elements per workgroup

// ws layout (in floats): transposed weights, ~650 KB total
#define W1T_OFF  0                     // [120][256]
#define W2IT_OFF 30720                 // [256][256]
#define W2RT_OFF 96256                 // [256][256]
#define W3T_OFF  161792                // [256][12]

// ---------------- prep: transpose weights into ws ----------------
__global__ void prep_kernel(const float* __restrict__ W1, const float* __restrict__ W2i,
                            const float* __restrict__ W2r, const float* __restrict__ W3,
                            float* __restrict__ ws) {
    int i = blockIdx.x * 256 + threadIdx.x;   // 0..65535
    int k = i >> 8, n = i & 255;
    ws[W2IT_OFF + i] = W2i[n * 256 + k];      // W2iT[k][n] = W2_in[n][k]
    ws[W2RT_OFF + i] = W2r[n * 256 + k];
    if (i < CD_ * N_) ws[W1T_OFF + i] = W1[n * CD_ + k];          // W1T[k][n], k<120
    if (i < N_ * OUT_) {
        int kk = i / OUT_, o = i - kk * OUT_;
        ws[W3T_OFF + i] = W3[o * N_ + kk];                        // W3T[k][o]
    }
}

// ---------------- ALIF update (exact reference order) ----------------
__device__ __forceinline__ void alif_step(float I, float& m, float& s, float& a,
                                          float al, float rh) {
    a = rh * a + (1.f - rh) * s;
    float Bth = 0.01f + 1.8f * a;
    m = al * m + (1.f - al) * I - Bth * s;
    s = ((m - Bth) > 0.f) ? 1.f : 0.f;
}

// gather sum of W^T columns (stride 256) listed in lst[0..cnt), 8 loads in flight
__device__ __forceinline__ float gather256(const float* __restrict__ Wt,
                                           const int* __restrict__ lst, int cnt, int n) {
    float acc = 0.f;
    int j = 0;
    for (; j + 8 <= cnt; j += 8) {
        const int4* lp = (const int4*)(lst + j);
        int4 ka = lp[0], kb = lp[1];
        float w0 = Wt[(ka.x << 8) + n];
        float w1 = Wt[(ka.y << 8) + n];
        float w2 = Wt[(ka.z << 8) + n];
        float w3 = Wt[(ka.w << 8) + n];
        float w4 = Wt[(kb.x << 8) + n];
        float w5 = Wt[(kb.y << 8) + n];
        float w6 = Wt[(kb.z << 8) + n];
        float w7 = Wt[(kb.w << 8) + n];
        acc += ((w0 + w1) + (w2 + w3)) + ((w4 + w5) + (w6 + w7));
    }
    for (; j < cnt; ++j) acc += Wt[(lst[j] << 8) + n];
    return acc;
}

// ---------------- the full 500-step scan, one WG per 2 batch rows ----------------
__global__ __launch_bounds__(256) void scan_kernel(
    const float* __restrict__ x, const float* __restrict__ thr_p,
    const float* __restrict__ b1, const float* __restrict__ b2i,
    const float* __restrict__ b2r, const float* __restrict__ b3,
    const float* __restrict__ tau_adp1, const float* __restrict__ tau_m1,
    const float* __restrict__ tau_adp2, const float* __restrict__ tau_m2,
    const float* __restrict__ tau_m3,
    const float* __restrict__ ws, float* __restrict__ out) {

    __shared__ __align__(16) float xsf[G_][CD_];
    __shared__ unsigned long long mk1s[G_][4], mk2s[G_][4];
    __shared__ __align__(16) int list1[G_][N_], list2[G_][N_];
    __shared__ float accs[G_][OUT_];

    const int tid  = threadIdx.x;
    const int n    = tid;
    const int wave = tid >> 6, lane = tid & 63;
    const int b0   = blockIdx.x * G_;

    const float* W1T  = ws + W1T_OFF;
    const float* W2iT = ws + W2IT_OFF;
    const float* W2rT = ws + W2RT_OFF;
    const float* W3T  = ws + W3T_OFF;

    const float thrv = thr_p[0];
    const float al1 = expf(-1.0f / tau_m1[n]);
    const float rh1 = expf(-1.0f / tau_adp1[n]);
    const float al2 = expf(-1.0f / tau_m2[n]);
    const float rh2 = expf(-1.0f / tau_adp2[n]);
    const float b1v = b1[n];
    const float b2v = b2i[n] + b2r[n];

    float m1[G_] = {0.f, 0.f}, s1[G_] = {0.f, 0.f}, a1[G_] = {0.01f, 0.01f};
    float m2[G_] = {0.f, 0.f}, s2[G_] = {0.f, 0.f}, a2[G_] = {0.01f, 0.01f};

    const bool is_out = (wave < G_) && (lane < OUT_);
    float al3 = 0.f, b3v = 0.f, m3 = 0.f, accv = 0.f;
    if (is_out) { al3 = expf(-1.0f / tau_m3[lane]); b3v = b3[lane]; }

    if (tid < 2 * 4) ((unsigned long long*)mk2s)[tid] = 0ull;   // s2(t=-1) = 0

    #pragma unroll 1
    for (int t = 0; t < T_; ++t) {
        // ---- stage ternary input spikes for this step into LDS ----
        if (tid < G_ * CD_) {
            int g = tid / CD_, j = tid - g * CD_;
            int c = j / D_, d = j - c * D_;
            float xv = x[((size_t)(b0 + g) * C_ + c) * (size_t)(T_ * D_) + t * D_ + d];
            float tp = ((xv - thrv)  > 0.f) ? 1.f : 0.f;   // bit-exact predicates
            float tn = ((-thrv - xv) > 0.f) ? 1.f : 0.f;
            xsf[g][j] = tp - tn;
        }
        __syncthreads();                                   // A

        // ---- i1 = xs @ W1^T + b1 (dense, W1T streamed from L2) ----
        float i10 = b1v, i11 = b1v;
        {
            const float4* xp0 = (const float4*)xsf[0];
            const float4* xp1 = (const float4*)xsf[1];
            const float* wc = W1T + n;
            #pragma unroll 6
            for (int k4 = 0; k4 < CD_ / 4; ++k4) {
                float4 a = xp0[k4], b = xp1[k4];
                float w0 = wc[(k4 * 4 + 0) << 8];
                float w1 = wc[(k4 * 4 + 1) << 8];
                float w2 = wc[(k4 * 4 + 2) << 8];
                float w3 = wc[(k4 * 4 + 3) << 8];
                i10 += a.x * w0 + a.y * w1 + a.z * w2 + a.w * w3;
                i11 += b.x * w0 + b.y * w1 + b.z * w2 + b.w * w3;
            }
        }

        // ---- layer-1 ALIF ----
        alif_step(i10, m1[0], s1[0], a1[0], al1, rh1);
        alif_step(i11, m1[1], s1[1], a1[1], al1, rh1);
        unsigned long long bal10 = __ballot(s1[0] > 0.5f);
        unsigned long long bal11 = __ballot(s1[1] > 0.5f);
        if (lane == 0) { mk1s[0][wave] = bal10; mk1s[1][wave] = bal11; }
        __syncthreads();                                   // B

        // ---- build active-index lists for s1 ----
        int c1[G_];
        #pragma unroll
        for (int g = 0; g < G_; ++g) {
            int base = 0, tot = 0;
            #pragma unroll
            for (int w = 0; w < 4; ++w) {
                int p = __popcll(mk1s[g][w]);
                tot += p;
                if (w < wave) base += p;
            }
            c1[g] = tot;
            unsigned long long bal = (g == 0) ? bal10 : bal11;
            if (s1[g] > 0.5f) {
                int rank = __popcll(bal & ((1ull << lane) - 1ull));
                list1[g][base + rank] = n;
            }
        }
        __syncthreads();                                   // C

        // ---- i2 = s1@W2_in^T + s2_prev@W2_rec^T + biases (sparse gathers) ----
        int c2[G_];
        #pragma unroll
        for (int g = 0; g < G_; ++g)
            c2[g] = __popcll(mk2s[g][0]) + __popcll(mk2s[g][1]) +
                    __popcll(mk2s[g][2]) + __popcll(mk2s[g][3]);

        float i20 = b2v + gather256(W2iT, list1[0], c1[0], n)
                        + gather256(W2rT, list2[0], c2[0], n);
        float i21 = b2v + gather256(W2iT, list1[1], c1[1], n)
                        + gather256(W2rT, list2[1], c2[1], n);

        alif_step(i20, m2[0], s2[0], a2[0], al2, rh2);
        alif_step(i21, m2[1], s2[1], a2[1], al2, rh2);
        __syncthreads();                                   // D (all reads of old mk2s/list2 done)

        unsigned long long bal20 = __ballot(s2[0] > 0.5f);
        unsigned long long bal21 = __ballot(s2[1] > 0.5f);
        if (lane == 0) { mk2s[0][wave] = bal20; mk2s[1][wave] = bal21; }
        __syncthreads();                                   // E

        #pragma unroll
        for (int g = 0; g < G_; ++g) {
            int base = 0;
            #pragma unroll
            for (int w = 0; w < 4; ++w) {
                int p = __popcll(mk2s[g][w]);
                if (w < wave) base += p;
            }
            unsigned long long bal = (g == 0) ? bal20 : bal21;
            if (s2[g] > 0.5f) {
                int rank = __popcll(bal & ((1ull << lane) - 1ull));
                list2[g][base + rank] = n;
            }
        }
        __syncthreads();                                   // F

        // ---- readout: i3 = s2@W3^T + b3 ; leaky integrate + accumulate ----
        if (is_out) {
            int g = wave, o = lane;
            int cc = __popcll(mk2s[g][0]) + __popcll(mk2s[g][1]) +
                     __popcll(mk2s[g][2]) + __popcll(mk2s[g][3]);
            float i3v = b3v;
            int j = 0;
            for (; j + 4 <= cc; j += 4) {
                const int4* lp = (const int4*)(list2[g] + j);
                int4 ka = lp[0];
                i3v += W3T[ka.x * OUT_ + o] + W3T[ka.y * OUT_ + o]
                     + W3T[ka.z * OUT_ + o] + W3T[ka.w * OUT_ + o];
            }
            for (; j < cc; ++j) i3v += W3T[list2[g][j] * OUT_ + o];
            m3 = al3 * m3 + (1.f - al3) * i3v;
            accv += m3;
        }
    }

    // ---- log_softmax(acc / T) ----
    if (is_out) accs[wave][lane] = accv;
    __syncthreads();
    if (is_out) {
        float L[OUT_];
        float mx = -1e30f;
        #pragma unroll
        for (int o2 = 0; o2 < OUT_; ++o2) {
            L[o2] = accs[wave][o2] / 500.0f;
            mx = fmaxf(mx, L[o2]);
        }
        float se = 0.f;
        #pragma unroll
        for (int o2 = 0; o2 < OUT_; ++o2) se += expf(L[o2] - mx);
        out[(b0 + wave) * OUT_ + lane] = L[lane] - mx - logf(se);
    }
}

// ---------------- host ----------------
extern "C" void kernel_launch(void* const* d_in, const int* in_sizes, int n_in,
                              void* d_out, int out_size, void* d_ws, size_t ws_size,
                              hipStream_t stream) {
    (void)in_sizes; (void)n_in; (void)out_size; (void)ws_size;
    const float* x        = (const float*)d_in[0];
    const float* thr      = (const float*)d_in[1];
    const float* W1       = (const float*)d_in[2];
    const float* b1       = (const float*)d_in[3];
    const float* W2_in    = (const float*)d_in[4];
    const float* b2_in    = (const float*)d_in[5];
    const float* W2_rec   = (const float*)d_in[6];
    const float* b2_rec   = (const float*)d_in[7];
    const float* W3       = (const float*)d_in[8];
    const float* b3       = (const float*)d_in[9];
    const float* tau_adp1 = (const float*)d_in[10];
    const float* tau_m1   = (const float*)d_in[11];
    const float* tau_adp2 = (const float*)d_in[12];
    const float* tau_m2   = (const float*)d_in[13];
    const float* tau_m3   = (const float*)d_in[14];
    float* ws  = (float*)d_ws;
    float* out = (float*)d_out;

    // transpose weights into ws (ws re-poisoned every launch -> redo every call)
    prep_kernel<<<256, 256, 0, stream>>>(W1, W2_in, W2_rec, W3, ws);
    // full sequential scan, one workgroup per 2 batch rows
    scan_kernel<<<B_ / G_, 256, 0, stream>>>(x, thr, b1, b2_in, b2_rec, b3,
                                             tau_adp1, tau_m1, tau_adp2, tau_m2, tau_m3,
                                             ws, out);
}

// Round 2
// 2783.168 us; speedup vs baseline: 1.2402x; 1.2402x over previous
//
#include <hip/hip_runtime.h>
#include <math.h>

// Problem constants (match reference)
#define B_   512
#define C_   3
#define T_   500
#define D_   40
#define CD_  120          // C*D
#define N_   256
#define OUT_ 12

// ws layout (floats). W2/W3 tables have a 257th all-zero row (index 256) so
// spike lists can be padded to a multiple of 8 with index 256 (no-op adds).
#define W1T_OFF  0                         // [120][256]
#define W2IT_OFF 30720                     // [257][256]
#define W2RT_OFF (30720 + 65792)           // [257][256]
#define W3T_OFF  (30720 + 2*65792)         // [257][12]

// ---------------- prep: transpose weights into ws, add zero pad rows ----------------
__global__ void prep_kernel(const float* __restrict__ W1, const float* __restrict__ W2i,
                            const float* __restrict__ W2r, const float* __restrict__ W3,
                            float* __restrict__ ws) {
    int i = blockIdx.x * 256 + threadIdx.x;   // 0 .. 258*256-1
    int k = i >> 8, n = i & 255;
    if (k < 256) {
        ws[W2IT_OFF + i] = W2i[n * 256 + k];  // W2iT[k][n]
        ws[W2RT_OFF + i] = W2r[n * 256 + k];
    } else if (k == 256) {
        ws[W2IT_OFF + i] = 0.f;               // zero pad row
        ws[W2RT_OFF + i] = 0.f;
    }
    if (i < CD_ * N_) ws[W1T_OFF + i] = W1[n * CD_ + k];          // W1T[k][n]
    if (i < 257 * OUT_) {
        int kk = i / OUT_, o = i - kk * OUT_;
        ws[W3T_OFF + i] = (kk < 256) ? W3[o * N_ + kk] : 0.f;     // W3T[k][o] + zero row
    }
}

// ---------------- ALIF update (exact reference order) ----------------
__device__ __forceinline__ void alif_step(float I, float& m, float& s, float& a,
                                          float al, float rh) {
    a = rh * a + (1.f - rh) * s;
    float Bth = 0.01f + 1.8f * a;
    m = al * m + (1.f - al) * I - Bth * s;
    s = ((m - Bth) > 0.f) ? 1.f : 0.f;
}

// gather over 4 per-wave segments; counts are pre-padded to multiples of 8
// (pad entries index the zero row), so every batch is exactly 8 loads in flight.
__device__ __forceinline__ float gatherseg(const float* __restrict__ Wt,
                                           const int* __restrict__ lst,
                                           int4 c, int n) {
    float acc = 0.f;
    #pragma unroll
    for (int w = 0; w < 4; ++w) {
        int cnt = (w == 0) ? c.x : (w == 1) ? c.y : (w == 2) ? c.z : c.w;
        const int* L = lst + (w << 6);
        for (int j = 0; j < cnt; j += 8) {
            int4 ka = *(const int4*)(L + j);
            int4 kb = *(const int4*)(L + j + 4);
            float w0 = Wt[(ka.x << 8) + n];
            float w1 = Wt[(ka.y << 8) + n];
            float w2 = Wt[(ka.z << 8) + n];
            float w3 = Wt[(ka.w << 8) + n];
            float w4 = Wt[(kb.x << 8) + n];
            float w5 = Wt[(kb.y << 8) + n];
            float w6 = Wt[(kb.z << 8) + n];
            float w7 = Wt[(kb.w << 8) + n];
            acc += ((w0 + w1) + (w2 + w3)) + ((w4 + w5) + (w6 + w7));
        }
    }
    return acc;
}

// ---------------- full 500-step scan, ONE batch row per workgroup ----------------
__global__ __launch_bounds__(256) void scan_kernel(
    const float* __restrict__ x, const float* __restrict__ thr_p,
    const float* __restrict__ b1, const float* __restrict__ b2i,
    const float* __restrict__ b2r, const float* __restrict__ b3,
    const float* __restrict__ tau_adp1, const float* __restrict__ tau_m1,
    const float* __restrict__ tau_adp2, const float* __restrict__ tau_m2,
    const float* __restrict__ tau_m3,
    const float* __restrict__ ws, float* __restrict__ out) {

    __shared__ __align__(16) float xsf[128];
    __shared__ __align__(16) int cw1[4];
    __shared__ __align__(16) int cw2[2][4];
    __shared__ __align__(16) int list1[4 * 64];
    __shared__ __align__(16) int list2[2][4 * 64];

    const int tid  = threadIdx.x;
    const int wave = tid >> 6, lane = tid & 63;
    const int b    = blockIdx.x;

    const float* W1T  = ws + W1T_OFF;
    const float* W2iT = ws + W2IT_OFF;
    const float* W2rT = ws + W2RT_OFF;
    const float* W3T  = ws + W3T_OFF;

    const float thrv = thr_p[0];
    const float al1 = expf(-1.0f / tau_m1[tid]);
    const float rh1 = expf(-1.0f / tau_adp1[tid]);
    const float al2 = expf(-1.0f / tau_m2[tid]);
    const float rh2 = expf(-1.0f / tau_adp2[tid]);
    const float b1v = b1[tid];
    const float b2v = b2i[tid] + b2r[tid];

    float m1 = 0.f, s1 = 0.f, a1 = 0.01f;
    float m2 = 0.f, s2 = 0.f, a2 = 0.01f;

    // readout roles: threads 0..47 (all wave 0): o = tid%12, wseg = tid/12
    const int o    = tid % 12;
    const int wseg = tid / 12;
    float al3 = 0.f, b3v = 0.f, m3 = 0.f, accv = 0.f;
    if (tid < OUT_) { al3 = expf(-1.0f / tau_m3[tid]); b3v = b3[tid]; }

    if (tid < 4) cw2[1][tid] = 0;   // s2(t=-1) empty (t=0 reads parity 1)

    // x prefetch pointer: thread j<120 handles input j = c*40+d
    const float* xp = nullptr;
    float xv = 0.f;
    if (tid < CD_) {
        int c = tid / D_, d = tid - c * D_;
        xp = x + (size_t)(b * C_ + c) * (T_ * D_) + d;
        xv = xp[0];
    }

    const unsigned long long lmask = (1ull << lane) - 1ull;

    #pragma unroll 1
    for (int t = 0; t < T_; ++t) {
        const int pp = t & 1, pq = pp ^ 1;

        // ---- stage ternary input spikes (from prefetched regs) ----
        if (tid < CD_) {
            float tp = ((xv - thrv)  > 0.f) ? 1.f : 0.f;
            float tn = ((-thrv - xv) > 0.f) ? 1.f : 0.f;
            xsf[tid] = tp - tn;
        }
        __syncthreads();                                   // A
        if (tid < CD_) {
            int tn1 = (t + 1 < T_) ? (t + 1) : (T_ - 1);
            xv = xp[tn1 * D_];                             // prefetch next step
        }

        // ---- i1 = xs @ W1^T + b1 (dense) ----
        float i1 = b1v;
        {
            const float4* xq = (const float4*)xsf;
            const float* wc = W1T + tid;
            #pragma unroll 15
            for (int k4 = 0; k4 < CD_ / 4; ++k4) {
                float4 a = xq[k4];
                float w0 = wc[(k4 * 4 + 0) << 8];
                float w1 = wc[(k4 * 4 + 1) << 8];
                float w2 = wc[(k4 * 4 + 2) << 8];
                float w3 = wc[(k4 * 4 + 3) << 8];
                i1 += a.x * w0 + a.y * w1 + a.z * w2 + a.w * w3;
            }
        }

        // ---- layer-1 ALIF + segmented list build (wave-local, no extra barrier) ----
        alif_step(i1, m1, s1, a1, al1, rh1);
        {
            unsigned long long bal = __ballot(s1 > 0.5f);
            int cnt  = __popcll(bal);
            int cpad = (cnt + 7) & ~7;
            if (s1 > 0.5f) {
                int rank = __popcll(bal & lmask);
                list1[(wave << 6) + rank] = tid;
            } else {
                int nrank = __popcll(~bal & lmask);
                if (nrank < cpad - cnt) list1[(wave << 6) + cnt + nrank] = 256; // pad -> zero row
            }
            if (lane == 0) cw1[wave] = cpad;
        }
        __syncthreads();                                   // B

        // ---- i2 = s1@W2_in^T + s2_prev@W2_rec^T + biases (sparse gathers) ----
        int4 c1 = *(const int4*)cw1;
        int4 c2 = *(const int4*)cw2[pq];
        float i2 = b2v + gatherseg(W2iT, list1, c1, tid)
                       + gatherseg(W2rT, list2[pq], c2, tid);

        alif_step(i2, m2, s2, a2, al2, rh2);
        {
            unsigned long long bal = __ballot(s2 > 0.5f);
            int cnt  = __popcll(bal);
            int cpad = (cnt + 7) & ~7;
            if (s2 > 0.5f) {
                int rank = __popcll(bal & lmask);
                list2[pp][(wave << 6) + rank] = tid;
            } else {
                int nrank = __popcll(~bal & lmask);
                if (nrank < cpad - cnt) list2[pp][(wave << 6) + cnt + nrank] = 256;
            }
            if (lane == 0) cw2[pp][wave] = cpad;
        }
        __syncthreads();                                   // E

        // ---- readout: 48 threads (4 segments x 12 outputs), shfl-reduce, no barrier ----
        if (wave == 0) {
            float part = 0.f;
            if (lane < 48) {
                int cc = cw2[pp][wseg];
                const int* L = &list2[pp][wseg << 6];
                for (int j = 0; j < cc; j += 4) {
                    int4 ka = *(const int4*)(L + j);
                    part += (W3T[ka.x * OUT_ + o] + W3T[ka.y * OUT_ + o])
                          + (W3T[ka.z * OUT_ + o] + W3T[ka.w * OUT_ + o]);
                }
            }
            part += __shfl(part, lane + 24);   // w0+=w2, w1+=w3
            part += __shfl(part, lane + 12);   // w0+=w1
            if (lane < OUT_) {
                float i3 = b3v + part;
                m3 = al3 * m3 + (1.f - al3) * i3;
                accv += m3;
            }
        }
    }

    // ---- log_softmax(acc / T) : wave 0, lanes 0..11 hold accv ----
    if (wave == 0) {
        float mx = -1e30f;
        #pragma unroll
        for (int o2 = 0; o2 < OUT_; ++o2)
            mx = fmaxf(mx, __shfl(accv / 500.0f, o2));
        float L = accv / 500.0f;
        float e = (lane < OUT_) ? expf(L - mx) : 0.f;
        float se = e;
        #pragma unroll
        for (int off = 1; off < 16; off <<= 1)   // lanes 0..11 live in 0..15 range
            se += __shfl_down(se, off);
        se = __shfl(se, 0);
        if (lane < OUT_)
            out[b * OUT_ + lane] = L - mx - logf(se);
    }
}

// ---------------- host ----------------
extern "C" void kernel_launch(void* const* d_in, const int* in_sizes, int n_in,
                              void* d_out, int out_size, void* d_ws, size_t ws_size,
                              hipStream_t stream) {
    (void)in_sizes; (void)n_in; (void)out_size; (void)ws_size;
    const float* x        = (const float*)d_in[0];
    const float* thr      = (const float*)d_in[1];
    const float* W1       = (const float*)d_in[2];
    const float* b1       = (const float*)d_in[3];
    const float* W2_in    = (const float*)d_in[4];
    const float* b2_in    = (const float*)d_in[5];
    const float* W2_rec   = (const float*)d_in[6];
    const float* b2_rec   = (const float*)d_in[7];
    const float* W3       = (const float*)d_in[8];
    const float* b3       = (const float*)d_in[9];
    const float* tau_adp1 = (const float*)d_in[10];
    const float* tau_m1   = (const float*)d_in[11];
    const float* tau_adp2 = (const float*)d_in[12];
    const float* tau_m2   = (const float*)d_in[13];
    const float* tau_m3   = (const float*)d_in[14];
    float* ws  = (float*)d_ws;
    float* out = (float*)d_out;

    prep_kernel<<<258, 256, 0, stream>>>(W1, W2_in, W2_rec, W3, ws);
    scan_kernel<<<B_, 256, 0, stream>>>(x, thr, b1, b2_in, b2_rec, b3,
                                        tau_adp1, tau_m1, tau_adp2, tau_m2, tau_m3,
                                        ws, out);
}

// Round 3
// 2752.076 us; speedup vs baseline: 1.2542x; 1.0113x over previous
//
#include <hip/hip_runtime.h>
#include <math.h>

#define B_   512
#define C_   3
#define T_   500
#define D_   40
#define CD_  120
#define N_   256
#define OUT_ 12
#define TILE 8
#define NTILE 63        // 63*8 = 504 >= 500

// ws layout (floats). W2 tables have a 257th all-zero row (index 256) for pads.
#define W1T_OFF  0                      // [120][256]
#define W2IT_OFF 30720                  // [257][256]
#define W2RT_OFF (30720 + 65792)        // [257][256]

// ---------------- prep: transpose weights into ws, add zero pad rows ----------------
__global__ void prep_kernel(const float* __restrict__ W1, const float* __restrict__ W2i,
                            const float* __restrict__ W2r, float* __restrict__ ws) {
    int i = blockIdx.x * 256 + threadIdx.x;   // 0 .. 257*256-1
    int k = i >> 8, n = i & 255;
    if (k < 256) {
        ws[W2IT_OFF + i] = W2i[n * 256 + k];
        ws[W2RT_OFF + i] = W2r[n * 256 + k];
    } else if (k == 256) {
        ws[W2IT_OFF + i] = 0.f;
        ws[W2RT_OFF + i] = 0.f;
    }
    if (i < CD_ * N_) ws[W1T_OFF + i] = W1[n * CD_ + k];
}

// ---------------- ALIF update (exact reference order) ----------------
__device__ __forceinline__ void alif_step(float I, float& m, float& s, float& a,
                                          float al, float rh) {
    a = rh * a + (1.f - rh) * s;
    float Bth = 0.01f + 1.8f * a;
    m = al * m + (1.f - al) * I - Bth * s;
    s = ((m - Bth) > 0.f) ? 1.f : 0.f;
}

// union gather: rows listed per wave-segment, each row has a float2 {g0,g1} mask
__device__ __forceinline__ void gather_union(const float* __restrict__ Wt,
                                             const int* __restrict__ IL,
                                             const float2* __restrict__ MF,
                                             const int* __restrict__ CW,
                                             int n, float& g0, float& g1) {
    #pragma unroll
    for (int sg = 0; sg < 4; ++sg) {
        int cnt = CW[sg];
        const int* L = IL + sg * 72;
        const float2* M = MF + sg * 72;
        for (int j = 0; j < cnt; j += 8) {
            int4 ia = *(const int4*)(L + j);
            int4 ib = *(const int4*)(L + j + 4);
            float4 m01 = *(const float4*)(M + j);
            float4 m23 = *(const float4*)(M + j + 2);
            float4 m45 = *(const float4*)(M + j + 4);
            float4 m67 = *(const float4*)(M + j + 6);
            float w0 = Wt[(ia.x << 8) + n];
            float w1 = Wt[(ia.y << 8) + n];
            float w2 = Wt[(ia.z << 8) + n];
            float w3 = Wt[(ia.w << 8) + n];
            float w4 = Wt[(ib.x << 8) + n];
            float w5 = Wt[(ib.y << 8) + n];
            float w6 = Wt[(ib.z << 8) + n];
            float w7 = Wt[(ib.w << 8) + n];
            g0 += w0 * m01.x; g1 += w0 * m01.y;
            g0 += w1 * m01.z; g1 += w1 * m01.w;
            g0 += w2 * m23.x; g1 += w2 * m23.y;
            g0 += w3 * m23.z; g1 += w3 * m23.w;
            g0 += w4 * m45.x; g1 += w4 * m45.y;
            g0 += w5 * m45.z; g1 += w5 * m45.w;
            g0 += w6 * m67.x; g1 += w6 * m67.y;
            g0 += w7 * m67.z; g1 += w7 * m67.w;
        }
    }
}

// ---------------- full scan: 2 batch rows per workgroup, 1 barrier/step ----------------
__global__ __launch_bounds__(256, 1) void scan_kernel(
    const float* __restrict__ x, const float* __restrict__ thr_p,
    const float* __restrict__ b1, const float* __restrict__ b2i,
    const float* __restrict__ b2r, const float* __restrict__ b3,
    const float* __restrict__ tau_adp1, const float* __restrict__ tau_m1,
    const float* __restrict__ tau_adp2, const float* __restrict__ tau_m2,
    const float* __restrict__ tau_m3, const float* __restrict__ W3,
    const float* __restrict__ ws, float* __restrict__ out) {

    __shared__ float xsf_t[2][TILE][CD_];                 // [g][tt][k] coalesced stage
    __shared__ __align__(16) float xsf8[2][CD_][TILE];    // [g][k][tt] for b128 reads
    __shared__ __align__(16) int    idx1[2][4][72];
    __shared__ __align__(16) int    idx2[2][4][72];
    __shared__ __align__(16) float2 mf1[2][4][72];
    __shared__ __align__(16) float2 mf2[2][4][72];
    __shared__ int cw1[2][4], cw2[2][4];
    __shared__ float red[2][OUT_][4];
    __shared__ float accs_l[2][OUT_];

    const int tid  = threadIdx.x;
    const int n    = tid;
    const int wave = tid >> 6, lane = tid & 63;
    const int b0   = blockIdx.x * 2;

    const float* W1T  = ws + W1T_OFF;
    const float* W2iT = ws + W2IT_OFF;
    const float* W2rT = ws + W2RT_OFF;

    const float thrv = thr_p[0];
    const float al1 = expf(-1.0f / tau_m1[n]);
    const float rh1 = expf(-1.0f / tau_adp1[n]);
    const float al2 = expf(-1.0f / tau_m2[n]);
    const float rh2 = expf(-1.0f / tau_adp2[n]);
    const float b1v = b1[n];
    const float b2v = b2i[n] + b2r[n];

    float al3j[OUT_];
    #pragma unroll
    for (int o = 0; o < OUT_; ++o) al3j[o] = expf(-1.0f / tau_m3[o]);

    float m1[2] = {0.f, 0.f}, s1f[2] = {0.f, 0.f}, a1v[2] = {0.01f, 0.01f};
    float m2[2] = {0.f, 0.f}, s2f[2] = {0.f, 0.f}, a2v[2] = {0.01f, 0.01f};
    float S[2] = {0.f, 0.f};
    float P[2][OUT_];
    #pragma unroll
    for (int g = 0; g < 2; ++g)
        #pragma unroll
        for (int o = 0; o < OUT_; ++o) P[g][o] = 0.f;

    if (tid < 4) cw2[1][tid] = 0;   // t=0 reads parity 1: empty
    const unsigned long long lmask = (1ull << lane) - 1ull;

    // prefetch tile 0 into registers
    float xreg[8];
    #pragma unroll
    for (int j = 0; j < 8; ++j) {
        int idx = tid + j * 256;
        if (idx < 2 * TILE * CD_) {
            int g = idx / (TILE * CD_), r = idx % (TILE * CD_);
            int tt = r / CD_, k = r % CD_;
            int c = k / D_, d = k - c * D_;
            int tg = tt; if (tg > T_ - 1) tg = T_ - 1;
            xreg[j] = x[((b0 + g) * C_ + c) * (T_ * D_) + tg * D_ + d];
        }
    }

    #pragma unroll 1
    for (int it = 0; it < NTILE; ++it) {
        const int t0 = it * TILE;

        // ---- write staged regs to xsf_t as ternary ----
        #pragma unroll
        for (int j = 0; j < 8; ++j) {
            int idx = tid + j * 256;
            if (idx < 2 * TILE * CD_) {
                int g = idx / (TILE * CD_), r = idx % (TILE * CD_);
                int tt = r / CD_, k = r % CD_;
                float xv = xreg[j];
                float tp = ((xv - thrv)  > 0.f) ? 1.f : 0.f;
                float tn = ((-thrv - xv) > 0.f) ? 1.f : 0.f;
                xsf_t[g][tt][k] = tp - tn;
            }
        }
        __syncthreads();                                   // T1

        // ---- prefetch next tile ----
        if (it + 1 < NTILE) {
            const int t0n = (it + 1) * TILE;
            #pragma unroll
            for (int j = 0; j < 8; ++j) {
                int idx = tid + j * 256;
                if (idx < 2 * TILE * CD_) {
                    int g = idx / (TILE * CD_), r = idx % (TILE * CD_);
                    int tt = r / CD_, k = r % CD_;
                    int c = k / D_, d = k - c * D_;
                    int tg = t0n + tt; if (tg > T_ - 1) tg = T_ - 1;
                    xreg[j] = x[((b0 + g) * C_ + c) * (T_ * D_) + tg * D_ + d];
                }
            }
        }

        // ---- transpose copy xsf_t -> xsf8 ----
        #pragma unroll
        for (int j = 0; j < 8; ++j) {
            int idx = tid + j * 256;
            if (idx < 2 * TILE * CD_) {
                int g = idx / (TILE * CD_), r = idx % (TILE * CD_);
                int k = r / TILE, tt = r % TILE;
                xsf8[g][k][tt] = xsf_t[g][tt][k];
            }
        }
        __syncthreads();                                   // T2

        // ---- i1 for the whole tile: W1T row read ONCE per 8 steps ----
        float i1a[2][TILE];
        #pragma unroll
        for (int g = 0; g < 2; ++g)
            #pragma unroll
            for (int tt = 0; tt < TILE; ++tt) i1a[g][tt] = 0.f;
        {
            const float* wc = W1T + n;
            #pragma unroll 4
            for (int k = 0; k < CD_; ++k) {
                float w = wc[k << 8];
                float4 xa0 = *(const float4*)&xsf8[0][k][0];
                float4 xa1 = *(const float4*)&xsf8[0][k][4];
                float4 xb0 = *(const float4*)&xsf8[1][k][0];
                float4 xb1 = *(const float4*)&xsf8[1][k][4];
                i1a[0][0] += xa0.x * w; i1a[0][1] += xa0.y * w;
                i1a[0][2] += xa0.z * w; i1a[0][3] += xa0.w * w;
                i1a[0][4] += xa1.x * w; i1a[0][5] += xa1.y * w;
                i1a[0][6] += xa1.z * w; i1a[0][7] += xa1.w * w;
                i1a[1][0] += xb0.x * w; i1a[1][1] += xb0.y * w;
                i1a[1][2] += xb0.z * w; i1a[1][3] += xb0.w * w;
                i1a[1][4] += xb1.x * w; i1a[1][5] += xb1.y * w;
                i1a[1][6] += xb1.z * w; i1a[1][7] += xb1.w * w;
            }
        }

        // ---- 8 steps ----
        #pragma unroll
        for (int tt = 0; tt < TILE; ++tt) {
            const int t = t0 + tt;
            const int pp = t & 1, pq = pp ^ 1;

            // layer-1 ALIF (both rows)
            alif_step(b1v + i1a[0][tt], m1[0], s1f[0], a1v[0], al1, rh1);
            alif_step(b1v + i1a[1][tt], m1[1], s1f[1], a1v[1], al1, rh1);

            // build union list1[pp]
            {
                bool p0 = s1f[0] > 0.5f, p1 = s1f[1] > 0.5f;
                unsigned long long bm0 = __ballot(p0), bm1 = __ballot(p1);
                unsigned long long bu = bm0 | bm1;
                int cnt = __popcll(bu), cpad = (cnt + 7) & ~7;
                if (p0 | p1) {
                    int r = __popcll(bu & lmask);
                    idx1[pp][wave][r] = n;
                    mf1[pp][wave][r] = make_float2(p0 ? 1.f : 0.f, p1 ? 1.f : 0.f);
                } else {
                    int nr = __popcll(~bu & lmask);
                    if (nr < cpad - cnt) {
                        int pos = cnt + nr;
                        idx1[pp][wave][pos] = 256;
                        mf1[pp][wave][pos] = make_float2(0.f, 0.f);
                    }
                }
                if (lane == 0) cw1[pp][wave] = cpad;
            }
            __syncthreads();                               // the ONE barrier per step

            // i2 = union gathers + biases
            float g0 = b2v, g1 = b2v;
            gather_union(W2iT, &idx1[pp][0][0], &mf1[pp][0][0], &cw1[pp][0], n, g0, g1);
            gather_union(W2rT, &idx2[pq][0][0], &mf2[pq][0][0], &cw2[pq][0], n, g0, g1);

            alif_step(g0, m2[0], s2f[0], a2v[0], al2, rh2);
            alif_step(g1, m2[1], s2f[1], a2v[1], al2, rh2);

            // build union list2[pp] (parity buffer: no WAR with in-flight reads of pq)
            {
                bool p0 = s2f[0] > 0.5f, p1 = s2f[1] > 0.5f;
                unsigned long long bm0 = __ballot(p0), bm1 = __ballot(p1);
                unsigned long long bu = bm0 | bm1;
                int cnt = __popcll(bu), cpad = (cnt + 7) & ~7;
                if (p0 | p1) {
                    int r = __popcll(bu & lmask);
                    idx2[pp][wave][r] = n;
                    mf2[pp][wave][r] = make_float2(p0 ? 1.f : 0.f, p1 ? 1.f : 0.f);
                } else {
                    int nr = __popcll(~bu & lmask);
                    if (nr < cpad - cnt) {
                        int pos = cnt + nr;
                        idx2[pp][wave][pos] = 256;
                        mf2[pp][wave][pos] = make_float2(0.f, 0.f);
                    }
                }
                if (lane == 0) cw2[pp][wave] = cpad;
            }

            // closed-form layer-3 state (guard padded steps t>=500)
            if (t < T_) {
                #pragma unroll
                for (int g = 0; g < 2; ++g) {
                    S[g] += s2f[g];
                    #pragma unroll
                    for (int o = 0; o < OUT_; ++o)
                        P[g][o] = al3j[o] * (P[g][o] + s2f[g]);
                }
            }
        }
    }

    // ---- epilogue: acc[g][o] = sum_n W3[o][n]*(S-P) + b3*C_o ; log_softmax ----
    #pragma unroll
    for (int g = 0; g < 2; ++g) {
        #pragma unroll
        for (int o = 0; o < OUT_; ++o) {
            float v = W3[o * N_ + n] * (S[g] - P[g][o]);
            v += __shfl_down(v, 32);
            v += __shfl_down(v, 16);
            v += __shfl_down(v, 8);
            v += __shfl_down(v, 4);
            v += __shfl_down(v, 2);
            v += __shfl_down(v, 1);
            if (lane == 0) red[g][o][wave] = v;
        }
    }
    __syncthreads();
    if (tid < 24) {
        int g = tid / OUT_, o = tid % OUT_;
        float acc = red[g][o][0] + red[g][o][1] + red[g][o][2] + red[g][o][3];
        float al3 = al3j[o];
        float alT = expf(-(float)T_ / tau_m3[o]);
        float Co  = (float)T_ - al3 * (1.f - alT) / (1.f - al3);
        acc += b3[o] * Co;
        accs_l[g][o] = acc / (float)T_;
    }
    __syncthreads();
    if (tid < 24) {
        int g = tid / OUT_, o = tid % OUT_;
        float mx = -1e30f;
        #pragma unroll
        for (int o2 = 0; o2 < OUT_; ++o2) mx = fmaxf(mx, accs_l[g][o2]);
        float se = 0.f;
        #pragma unroll
        for (int o2 = 0; o2 < OUT_; ++o2) se += expf(accs_l[g][o2] - mx);
        out[(b0 + g) * OUT_ + o] = accs_l[g][o] - mx - logf(se);
    }
}

// ---------------- host ----------------
extern "C" void kernel_launch(void* const* d_in, const int* in_sizes, int n_in,
                              void* d_out, int out_size, void* d_ws, size_t ws_size,
                              hipStream_t stream) {
    (void)in_sizes; (void)n_in; (void)out_size; (void)ws_size;
    const float* x        = (const float*)d_in[0];
    const float* thr      = (const float*)d_in[1];
    const float* W1       = (const float*)d_in[2];
    const float* b1       = (const float*)d_in[3];
    const float* W2_in    = (const float*)d_in[4];
    const float* b2_in    = (const float*)d_in[5];
    const float* W2_rec   = (const float*)d_in[6];
    const float* b2_rec   = (const float*)d_in[7];
    const float* W3       = (const float*)d_in[8];
    const float* b3       = (const float*)d_in[9];
    const float* tau_adp1 = (const float*)d_in[10];
    const float* tau_m1   = (const float*)d_in[11];
    const float* tau_adp2 = (const float*)d_in[12];
    const float* tau_m2   = (const float*)d_in[13];
    const float* tau_m3   = (const float*)d_in[14];
    float* ws  = (float*)d_ws;
    float* out = (float*)d_out;

    prep_kernel<<<257, 256, 0, stream>>>(W1, W2_in, W2_rec, ws);
    scan_kernel<<<B_ / 2, 256, 0, stream>>>(x, thr, b1, b2_in, b2_rec, b3,
                                            tau_adp1, tau_m1, tau_adp2, tau_m2,
                                            tau_m3, W3, ws, out);
}

// Round 4
// 1808.558 us; speedup vs baseline: 1.9086x; 1.5217x over previous
//
#include <hip/hip_runtime.h>
#include <math.h>

#define B_   512
#define C_   3
#define T_   500
#define D_   40
#define CD_  120
#define N_   256
#define OUT_ 12
#define TILE 8
#define NTILE 63        // 63*8 = 504 >= 500

// ws layout (floats). W2 tables have a 257th all-zero row (index 256) for pads.
#define W1T_OFF  0                      // [120][256]
#define W2IT_OFF 30720                  // [257][256]
#define W2RT_OFF (30720 + 65792)        // [257][256]

// ---------------- prep: transpose weights into ws, add zero pad rows ----------------
__global__ void prep_kernel(const float* __restrict__ W1, const float* __restrict__ W2i,
                            const float* __restrict__ W2r, float* __restrict__ ws) {
    int i = blockIdx.x * 256 + threadIdx.x;   // 0 .. 257*256-1
    int k = i >> 8, n = i & 255;
    if (k < 256) {
        ws[W2IT_OFF + i] = W2i[n * 256 + k];
        ws[W2RT_OFF + i] = W2r[n * 256 + k];
    } else if (k == 256) {
        ws[W2IT_OFF + i] = 0.f;
        ws[W2RT_OFF + i] = 0.f;
    }
    if (i < CD_ * N_) ws[W1T_OFF + i] = W1[n * CD_ + k];
}

// ---------------- ALIF update (exact reference order) ----------------
__device__ __forceinline__ void alif_step(float I, float& m, float& s, float& a,
                                          float al, float rh) {
    a = rh * a + (1.f - rh) * s;
    float Bth = 0.01f + 1.8f * a;
    m = al * m + (1.f - al) * I - Bth * s;
    s = ((m - Bth) > 0.f) ? 1.f : 0.f;
}

// one padded segment list, 16 loads in flight (counts are multiples of 8)
__device__ __forceinline__ void gather16(const float* __restrict__ Wt,
                                         const int* __restrict__ L,
                                         const float2* __restrict__ M,
                                         int cnt, int n, float& g0, float& g1) {
    int j = 0;
    for (; j + 16 <= cnt; j += 16) {
        int4 ia = *(const int4*)(L + j);
        int4 ib = *(const int4*)(L + j + 4);
        int4 ic = *(const int4*)(L + j + 8);
        int4 id = *(const int4*)(L + j + 12);
        float4 ma = *(const float4*)(M + j);
        float4 mb = *(const float4*)(M + j + 2);
        float4 mc = *(const float4*)(M + j + 4);
        float4 md = *(const float4*)(M + j + 6);
        float4 me = *(const float4*)(M + j + 8);
        float4 mf = *(const float4*)(M + j + 10);
        float4 mg = *(const float4*)(M + j + 12);
        float4 mh = *(const float4*)(M + j + 14);
        float w0  = Wt[(ia.x << 8) + n];
        float w1  = Wt[(ia.y << 8) + n];
        float w2  = Wt[(ia.z << 8) + n];
        float w3  = Wt[(ia.w << 8) + n];
        float w4  = Wt[(ib.x << 8) + n];
        float w5  = Wt[(ib.y << 8) + n];
        float w6  = Wt[(ib.z << 8) + n];
        float w7  = Wt[(ib.w << 8) + n];
        float w8  = Wt[(ic.x << 8) + n];
        float w9  = Wt[(ic.y << 8) + n];
        float w10 = Wt[(ic.z << 8) + n];
        float w11 = Wt[(ic.w << 8) + n];
        float w12 = Wt[(id.x << 8) + n];
        float w13 = Wt[(id.y << 8) + n];
        float w14 = Wt[(id.z << 8) + n];
        float w15 = Wt[(id.w << 8) + n];
        g0 += w0*ma.x;  g1 += w0*ma.y;  g0 += w1*ma.z;  g1 += w1*ma.w;
        g0 += w2*mb.x;  g1 += w2*mb.y;  g0 += w3*mb.z;  g1 += w3*mb.w;
        g0 += w4*mc.x;  g1 += w4*mc.y;  g0 += w5*mc.z;  g1 += w5*mc.w;
        g0 += w6*md.x;  g1 += w6*md.y;  g0 += w7*md.z;  g1 += w7*md.w;
        g0 += w8*me.x;  g1 += w8*me.y;  g0 += w9*me.z;  g1 += w9*me.w;
        g0 += w10*mf.x; g1 += w10*mf.y; g0 += w11*mf.z; g1 += w11*mf.w;
        g0 += w12*mg.x; g1 += w12*mg.y; g0 += w13*mg.z; g1 += w13*mg.w;
        g0 += w14*mh.x; g1 += w14*mh.y; g0 += w15*mh.z; g1 += w15*mh.w;
    }
    if (j < cnt) {   // remaining 8
        int4 ia = *(const int4*)(L + j);
        int4 ib = *(const int4*)(L + j + 4);
        float4 ma = *(const float4*)(M + j);
        float4 mb = *(const float4*)(M + j + 2);
        float4 mc = *(const float4*)(M + j + 4);
        float4 md = *(const float4*)(M + j + 6);
        float w0 = Wt[(ia.x << 8) + n];
        float w1 = Wt[(ia.y << 8) + n];
        float w2 = Wt[(ia.z << 8) + n];
        float w3 = Wt[(ia.w << 8) + n];
        float w4 = Wt[(ib.x << 8) + n];
        float w5 = Wt[(ib.y << 8) + n];
        float w6 = Wt[(ib.z << 8) + n];
        float w7 = Wt[(ib.w << 8) + n];
        g0 += w0*ma.x; g1 += w0*ma.y; g0 += w1*ma.z; g1 += w1*ma.w;
        g0 += w2*mb.x; g1 += w2*mb.y; g0 += w3*mb.z; g1 += w3*mb.w;
        g0 += w4*mc.x; g1 += w4*mc.y; g0 += w5*mc.z; g1 += w5*mc.w;
        g0 += w6*md.x; g1 += w6*md.y; g0 += w7*md.z; g1 += w7*md.w;
    }
}

// ------- full scan: 2 batch rows / WG, 512 threads (2 k-halves), 2 barriers/step -------
__global__ __launch_bounds__(512, 2) void scan_kernel(
    const float* __restrict__ x, const float* __restrict__ thr_p,
    const float* __restrict__ b1, const float* __restrict__ b2i,
    const float* __restrict__ b2r, const float* __restrict__ b3,
    const float* __restrict__ tau_adp1, const float* __restrict__ tau_m1,
    const float* __restrict__ tau_adp2, const float* __restrict__ tau_m2,
    const float* __restrict__ tau_m3, const float* __restrict__ W3,
    const float* __restrict__ ws, float* __restrict__ out) {

    __shared__ float xsf_t[2][TILE][CD_];                 // [g][tt][k] staging
    __shared__ __align__(16) float xsf8[2][CD_][TILE];    // [g][k][tt] broadcast reads
    __shared__ __align__(16) int    idx1[2][4][72];
    __shared__ __align__(16) int    idx2[2][4][72];
    __shared__ __align__(16) float2 mf1[2][4][72];
    __shared__ __align__(16) float2 mf2[2][4][72];
    __shared__ int cw1[2][4], cw2[2][4];
    __shared__ float part[2][2][N_];                      // [khalf][row][n]
    __shared__ float red[2][OUT_][4];
    __shared__ float accs_l[2][OUT_];

    const int tid  = threadIdx.x;        // 0..511
    const int n    = tid & 255;          // neuron
    const int h    = tid >> 8;           // k-half: gathers segments 2h, 2h+1
    const int wv   = tid >> 6;           // 0..7
    const int seg  = wv & 3;
    const int lane = tid & 63;
    const int b0   = blockIdx.x * 2;

    const float* W1T  = ws + W1T_OFF;
    const float* W2iT = ws + W2IT_OFF;
    const float* W2rT = ws + W2RT_OFF;

    const float thrv = thr_p[0];
    const float al1 = expf(-1.0f / tau_m1[n]);
    const float rh1 = expf(-1.0f / tau_adp1[n]);
    const float al2 = expf(-1.0f / tau_m2[n]);
    const float rh2 = expf(-1.0f / tau_adp2[n]);
    const float b1v = b1[n];
    const float b2v = b2i[n] + b2r[n];

    float al3j[OUT_];
    #pragma unroll
    for (int o = 0; o < OUT_; ++o) al3j[o] = expf(-1.0f / tau_m3[o]);

    // ALIF state, replicated bitwise-identically in both halves
    float m1[2] = {0.f, 0.f}, s1f[2] = {0.f, 0.f}, a1v[2] = {0.01f, 0.01f};
    float m2[2] = {0.f, 0.f}, s2f[2] = {0.f, 0.f}, a2v[2] = {0.01f, 0.01f};
    float S[2] = {0.f, 0.f};
    float P[2][OUT_];
    #pragma unroll
    for (int g = 0; g < 2; ++g)
        #pragma unroll
        for (int o = 0; o < OUT_; ++o) P[g][o] = 0.f;

    if (tid < 4) cw2[1][tid] = 0;        // t=0 reads parity 1: empty
    const unsigned long long lmask = (1ull << lane) - 1ull;

    // x tile staging: 1920 elems, idx = tid + j*512
    float xreg[4];
    #pragma unroll
    for (int j = 0; j < 4; ++j) {
        int idx = tid + j * 512;
        if (idx < 2 * TILE * CD_) {
            int g = idx / (TILE * CD_), r = idx % (TILE * CD_);
            int tt = r / CD_, k = r % CD_;
            int c = k / D_, d = k - c * D_;
            int tg = tt; if (tg > T_ - 1) tg = T_ - 1;
            xreg[j] = x[((b0 + g) * C_ + c) * (T_ * D_) + tg * D_ + d];
        }
    }

    #pragma unroll 1
    for (int it = 0; it < NTILE; ++it) {
        const int t0 = it * TILE;

        #pragma unroll
        for (int j = 0; j < 4; ++j) {
            int idx = tid + j * 512;
            if (idx < 2 * TILE * CD_) {
                int g = idx / (TILE * CD_), r = idx % (TILE * CD_);
                int tt = r / CD_, k = r % CD_;
                float xv = xreg[j];
                float tp = ((xv - thrv)  > 0.f) ? 1.f : 0.f;
                float tn = ((-thrv - xv) > 0.f) ? 1.f : 0.f;
                xsf_t[g][tt][k] = tp - tn;
            }
        }
        __syncthreads();                                   // T1

        if (it + 1 < NTILE) {
            const int t0n = (it + 1) * TILE;
            #pragma unroll
            for (int j = 0; j < 4; ++j) {
                int idx = tid + j * 512;
                if (idx < 2 * TILE * CD_) {
                    int g = idx / (TILE * CD_), r = idx % (TILE * CD_);
                    int tt = r / CD_, k = r % CD_;
                    int c = k / D_, d = k - c * D_;
                    int tg = t0n + tt; if (tg > T_ - 1) tg = T_ - 1;
                    xreg[j] = x[((b0 + g) * C_ + c) * (T_ * D_) + tg * D_ + d];
                }
            }
        }

        #pragma unroll
        for (int j = 0; j < 4; ++j) {
            int idx = tid + j * 512;
            if (idx < 2 * TILE * CD_) {
                int g = idx / (TILE * CD_), r = idx % (TILE * CD_);
                int k = r / TILE, tt = r % TILE;
                xsf8[g][k][tt] = xsf_t[g][tt][k];
            }
        }
        __syncthreads();                                   // T2

        // ---- i1 for the tile (replicated in both halves; L1-hot for the twin) ----
        float i1a[2][TILE];
        #pragma unroll
        for (int g = 0; g < 2; ++g)
            #pragma unroll
            for (int tt = 0; tt < TILE; ++tt) i1a[g][tt] = 0.f;
        {
            const float* wc = W1T + n;
            #pragma unroll 4
            for (int k = 0; k < CD_; ++k) {
                float w = wc[k << 8];
                float4 xa0 = *(const float4*)&xsf8[0][k][0];
                float4 xa1 = *(const float4*)&xsf8[0][k][4];
                float4 xb0 = *(const float4*)&xsf8[1][k][0];
                float4 xb1 = *(const float4*)&xsf8[1][k][4];
                i1a[0][0] += xa0.x * w; i1a[0][1] += xa0.y * w;
                i1a[0][2] += xa0.z * w; i1a[0][3] += xa0.w * w;
                i1a[0][4] += xa1.x * w; i1a[0][5] += xa1.y * w;
                i1a[0][6] += xa1.z * w; i1a[0][7] += xa1.w * w;
                i1a[1][0] += xb0.x * w; i1a[1][1] += xb0.y * w;
                i1a[1][2] += xb0.z * w; i1a[1][3] += xb0.w * w;
                i1a[1][4] += xb1.x * w; i1a[1][5] += xb1.y * w;
                i1a[1][6] += xb1.z * w; i1a[1][7] += xb1.w * w;
            }
        }

        // ---- 8 steps ----
        #pragma unroll
        for (int tt = 0; tt < TILE; ++tt) {
            const int t = t0 + tt;
            const int pp = t & 1, pq = pp ^ 1;

            alif_step(b1v + i1a[0][tt], m1[0], s1f[0], a1v[0], al1, rh1);
            alif_step(b1v + i1a[1][tt], m1[1], s1f[1], a1v[1], al1, rh1);

            // union list1: built by half-0 waves (ballots identical in both halves)
            {
                bool p0 = s1f[0] > 0.5f, p1 = s1f[1] > 0.5f;
                unsigned long long bu = __ballot(p0) | __ballot(p1);
                if (h == 0) {
                    int cnt = __popcll(bu), cpad = (cnt + 7) & ~7;
                    if (p0 | p1) {
                        int r = __popcll(bu & lmask);
                        idx1[pp][seg][r] = n;
                        mf1[pp][seg][r] = make_float2(p0 ? 1.f : 0.f, p1 ? 1.f : 0.f);
                    } else {
                        int nr = __popcll(~bu & lmask);
                        if (nr < cpad - cnt) {
                            idx1[pp][seg][cnt + nr] = 256;
                            mf1[pp][seg][cnt + nr] = make_float2(0.f, 0.f);
                        }
                    }
                    if (lane == 0) cw1[pp][seg] = cpad;
                }
            }
            __syncthreads();                               // B1: list1 ready

            // gather this thread's 2 segments of both lists
            float g0 = 0.f, g1 = 0.f;
            {
                int sa = 2 * h, sb = 2 * h + 1;
                gather16(W2iT, &idx1[pp][sa][0], &mf1[pp][sa][0], cw1[pp][sa], n, g0, g1);
                gather16(W2iT, &idx1[pp][sb][0], &mf1[pp][sb][0], cw1[pp][sb], n, g0, g1);
                gather16(W2rT, &idx2[pq][sa][0], &mf2[pq][sa][0], cw2[pq][sa], n, g0, g1);
                gather16(W2rT, &idx2[pq][sb][0], &mf2[pq][sb][0], cw2[pq][sb], n, g0, g1);
            }
            part[h][0][n] = g0;
            part[h][1][n] = g1;
            __syncthreads();                               // B2: partials ready

            float i20 = b2v + part[0][0][n] + part[1][0][n];
            float i21 = b2v + part[0][1][n] + part[1][1][n];
            alif_step(i20, m2[0], s2f[0], a2v[0], al2, rh2);
            alif_step(i21, m2[1], s2f[1], a2v[1], al2, rh2);

            // union list2 (parity pp): built by half-1 waves
            {
                bool p0 = s2f[0] > 0.5f, p1 = s2f[1] > 0.5f;
                unsigned long long bu = __ballot(p0) | __ballot(p1);
                if (h == 1) {
                    int cnt = __popcll(bu), cpad = (cnt + 7) & ~7;
                    if (p0 | p1) {
                        int r = __popcll(bu & lmask);
                        idx2[pp][seg][r] = n;
                        mf2[pp][seg][r] = make_float2(p0 ? 1.f : 0.f, p1 ? 1.f : 0.f);
                    } else {
                        int nr = __popcll(~bu & lmask);
                        if (nr < cpad - cnt) {
                            idx2[pp][seg][cnt + nr] = 256;
                            mf2[pp][seg][cnt + nr] = make_float2(0.f, 0.f);
                        }
                    }
                    if (lane == 0) cw2[pp][seg] = cpad;
                }
            }

            // closed-form layer-3 state (replicated; half 0's copy used at end)
            if (t < T_) {
                #pragma unroll
                for (int g = 0; g < 2; ++g) {
                    S[g] += s2f[g];
                    #pragma unroll
                    for (int o = 0; o < OUT_; ++o)
                        P[g][o] = al3j[o] * (P[g][o] + s2f[g]);
                }
            }
        }
    }

    // ---- epilogue (half 0): acc = W3·(S-P) + b3*C_o ; log_softmax ----
    if (h == 0) {
        #pragma unroll
        for (int g = 0; g < 2; ++g) {
            #pragma unroll
            for (int o = 0; o < OUT_; ++o) {
                float v = W3[o * N_ + n] * (S[g] - P[g][o]);
                v += __shfl_down(v, 32);
                v += __shfl_down(v, 16);
                v += __shfl_down(v, 8);
                v += __shfl_down(v, 4);
                v += __shfl_down(v, 2);
                v += __shfl_down(v, 1);
                if (lane == 0) red[g][o][seg] = v;
            }
        }
    }
    __syncthreads();
    if (tid < 24) {
        int g = tid / OUT_, o = tid % OUT_;
        float acc = red[g][o][0] + red[g][o][1] + red[g][o][2] + red[g][o][3];
        float al3 = al3j[o];
        float alT = expf(-(float)T_ / tau_m3[o]);
        float Co  = (float)T_ - al3 * (1.f - alT) / (1.f - al3);
        acc += b3[o] * Co;
        accs_l[g][o] = acc / (float)T_;
    }
    __syncthreads();
    if (tid < 24) {
        int g = tid / OUT_, o = tid % OUT_;
        float mx = -1e30f;
        #pragma unroll
        for (int o2 = 0; o2 < OUT_; ++o2) mx = fmaxf(mx, accs_l[g][o2]);
        float se = 0.f;
        #pragma unroll
        for (int o2 = 0; o2 < OUT_; ++o2) se += expf(accs_l[g][o2] - mx);
        out[(b0 + g) * OUT_ + o] = accs_l[g][o] - mx - logf(se);
    }
}

// ---------------- host ----------------
extern "C" void kernel_launch(void* const* d_in, const int* in_sizes, int n_in,
                              void* d_out, int out_size, void* d_ws, size_t ws_size,
                              hipStream_t stream) {
    (void)in_sizes; (void)n_in; (void)out_size; (void)ws_size;
    const float* x        = (const float*)d_in[0];
    const float* thr      = (const float*)d_in[1];
    const float* W1       = (const float*)d_in[2];
    const float* b1       = (const float*)d_in[3];
    const float* W2_in    = (const float*)d_in[4];
    const float* b2_in    = (const float*)d_in[5];
    const float* W2_rec   = (const float*)d_in[6];
    const float* b2_rec   = (const float*)d_in[7];
    const float* W3       = (const float*)d_in[8];
    const float* b3       = (const float*)d_in[9];
    const float* tau_adp1 = (const float*)d_in[10];
    const float* tau_m1   = (const float*)d_in[11];
    const float* tau_adp2 = (const float*)d_in[12];
    const float* tau_m2   = (const float*)d_in[13];
    const float* tau_m3   = (const float*)d_in[14];
    float* ws  = (float*)d_ws;
    float* out = (float*)d_out;

    prep_kernel<<<257, 256, 0, stream>>>(W1, W2_in, W2_rec, ws);
    scan_kernel<<<B_ / 2, 512, 0, stream>>>(x, thr, b1, b2_in, b2_rec, b3,
                                            tau_adp1, tau_m1, tau_adp2, tau_m2,
                                            tau_m3, W3, ws, out);
}